// Round 8
// baseline (1522.447 us; speedup 1.0000x reference)
//
#include <hip/hip_runtime.h>
#include <math.h>

#define NODES 81
#define T_STEPS 12
#define NSEQ 41472
#define HID 128
#define SEQB 32               // sequences per block

typedef unsigned short ushort;
typedef unsigned int uint;
typedef __attribute__((ext_vector_type(8))) short short8;
typedef __attribute__((ext_vector_type(4))) float f32x4;

#define MFMA(A, B, C) __builtin_amdgcn_mfma_f32_16x16x32_bf16((A), (B), (C), 0, 0, 0)

__device__ __forceinline__ ushort f2bf(float v) {
    unsigned int u = __float_as_uint(v);
    unsigned int r = (u + 0x7FFFu + ((u >> 16) & 1u)) >> 16;
    return (ushort)r;
}
__device__ __forceinline__ float bf2f(ushort s) {
    return __uint_as_float(((unsigned int)s) << 16);
}
// fast sigmoid/tanh: v_exp_f32 (2^x) + v_rcp_f32, ~2e-7 rel err
__device__ __forceinline__ float sigf(float v) {
    return __builtin_amdgcn_rcpf(1.f + __builtin_amdgcn_exp2f(v * -1.442695041f));
}
__device__ __forceinline__ float tanhf_(float v) {
    return fmaf(2.f, __builtin_amdgcn_rcpf(1.f + __builtin_amdgcn_exp2f(v * -2.885390082f)), -1.f);
}

// ---------------------------------------------------------------------------
// Prep: MFMA-fragment-major split-bf16 weights, ORIGINAL gate order.
// Layout per matrix: [ks(4)][nt(32)][sel(2)][lane(64)][j(8)] ushort,
// value = W[n*128+k]; k = ks*32 + (lane>>4)*8 + j, n = nt*16 + (lane&15).
// Gate type t, unit-group gr of a tile: nt = t*8 + gr.
// ---------------------------------------------------------------------------
__global__ void prep_kernel(const float* __restrict__ Whh0,
                            const float* __restrict__ Wih1,
                            const float* __restrict__ Whh1,
                            const float* __restrict__ bih0, const float* __restrict__ bhh0,
                            const float* __restrict__ bih1, const float* __restrict__ bhh1,
                            ushort* __restrict__ WF0,
                            ushort* __restrict__ WF1i,
                            ushort* __restrict__ WF1h,
                            float* __restrict__ b0p,
                            float* __restrict__ b1p)
{
    int idx = blockIdx.x * 256 + threadIdx.x;   // 394240 total
    if (idx < 393216) {
        int mat = idx >> 17;              // 131072 per matrix
        int li  = idx & 131071;
        int j   = li & 7;
        int l   = (li >> 3) & 63;
        int sel = (li >> 9) & 1;
        int nt  = (li >> 10) & 31;
        int ks  = (li >> 15) & 3;
        int k = ks * 32 + (l >> 4) * 8 + j;
        int n = nt * 16 + (l & 15);
        const float* W = (mat == 0) ? Whh0 : (mat == 1 ? Wih1 : Whh1);
        float v = W[n * 128 + k];
        ushort hs = f2bf(v);
        ushort ov = sel ? f2bf(v - bf2f(hs)) : hs;
        ushort* D = (mat == 0) ? WF0 : (mat == 1 ? WF1i : WF1h);
        D[li] = ov;
    } else if (idx < 393728) {
        int jp = idx - 393216;
        b0p[jp] = bih0[jp] + bhh0[jp];
    } else if (idx < 394240) {
        int jp = idx - 393728;
        b1p[jp] = bih1[jp] + bhh1[jp];
    }
}

// ---------------------------------------------------------------------------
// income = einsum('bta,an->bnt'); stored t-major: x[t][seq], seq = b*81+n
// ---------------------------------------------------------------------------
__global__ void income_kernel(const float* __restrict__ g_data,
                              const float* __restrict__ w,
                              float* __restrict__ x)
{
    int idx = blockIdx.x * 256 + threadIdx.x;   // 497664 exactly
    int n = idx % NODES;
    int r = idx / NODES;
    int t = r % T_STEPS;
    int b = r / T_STEPS;
    const float* grow = g_data + (b * T_STEPS + t) * NODES;
    float s = 0.f;
    #pragma unroll 3
    for (int a = 0; a < NODES; ++a)
        s += grow[a] * w[a * NODES + n];
    x[t * NSEQ + b * NODES + n] = s;
}

// ---------------------------------------------------------------------------
// Fused 2-layer LSTM + FC head on MFMA (split bf16), transpose-free,
// register-lean: layer-1 matmul split into two sequential passes so peak
// live regs ~= L0's (acc32 + A16 + B8 + ~30 state) < 128 -> no spill.
// Block = 32 seqs, 512 threads = 8 waves. Wave gr owns unit-group gr:
// n-tiles {gr, gr+8, gr+16, gr+24} (= i,f,g,o) x 2 m-tiles; lane holds all 4
// gate types of its unit in acc[mt][0..3] -> in-register activation.
// h-state double-buffered in LDS, A-frag layout hA[buf][kq16][m32][j8].
// 2 barriers/step.
// ---------------------------------------------------------------------------
__global__ __launch_bounds__(512, 2) void lstm_main(
    const float* __restrict__ x,        // [12][NSEQ]
    const ushort* __restrict__ WF0,
    const ushort* __restrict__ WF1i,
    const ushort* __restrict__ WF1h,
    const float* __restrict__ wih0,     // [512] original order
    const float* __restrict__ b0p,      // [512]
    const float* __restrict__ b1p,      // [512]
    const float* __restrict__ fc1_w,    // [32][128]
    const float* __restrict__ fc1_b,    // [32]
    const float* __restrict__ fc2_w,    // [32]
    const float* __restrict__ fc2_b,    // [1]
    float* __restrict__ out)            // [NSEQ]
{
    __shared__ __align__(16) ushort hA0h[8192];   // [2][kq16][m32][j8]
    __shared__ __align__(16) ushort hA0l[8192];
    __shared__ __align__(16) ushort hA1h[8192];
    __shared__ __align__(16) ushort hA1l[8192];

    const int tid = threadIdx.x;
    const int l   = tid & 63;
    const int gr  = tid >> 6;          // 0..7 unit-group
    const int l15 = l & 15;
    const int l16 = l >> 4;
    const int u   = gr * 16 + l15;     // owned unit 0..127
    const int seq0 = blockIdx.x * SEQB;

    for (int i = tid; i < 4096; i += 512) {
        ((uint*)hA0h)[i] = 0u; ((uint*)hA0l)[i] = 0u;
        ((uint*)hA1h)[i] = 0u; ((uint*)hA1l)[i] = 0u;
    }

    float wih[4], bb0[4], bb1[4];
    #pragma unroll
    for (int t4 = 0; t4 < 4; ++t4) {
        wih[t4] = wih0[t4 * 128 + u];
        bb0[t4] = b0p[t4 * 128 + u];
        bb1[t4] = b1p[t4 * 128 + u];
    }
    float c0[8], c1[8];                 // [mt*4+r]
    #pragma unroll
    for (int i = 0; i < 8; ++i) { c0[i] = 0.f; c1[i] = 0.f; }
    __syncthreads();

    int cur = 0;
    for (int t = 0; t < T_STEPS; ++t) {
        const int nxt = cur ^ 1;
        f32x4 acc[2][4];                // [mt][gate-type]

        // ===== layer 0 matmul: h0 @ Whh0 =====
        #pragma unroll
        for (int mt = 0; mt < 2; ++mt)
            #pragma unroll
            for (int t4 = 0; t4 < 4; ++t4) acc[mt][t4] = (f32x4){0.f, 0.f, 0.f, 0.f};
        #pragma unroll
        for (int ks = 0; ks < 4; ++ks) {
            const int ao = cur * 4096 + (ks * 4 + l16) * 256 + l15 * 8;
            short8 ah0 = *(const short8*)(hA0h + ao);
            short8 al0 = *(const short8*)(hA0l + ao);
            short8 ah1 = *(const short8*)(hA0h + ao + 128);
            short8 al1 = *(const short8*)(hA0l + ao + 128);
            #pragma unroll
            for (int t4 = 0; t4 < 4; ++t4) {
                const ushort* bp = WF0 + (size_t)((ks * 32 + t4 * 8 + gr) * 2) * 512 + l * 8;
                short8 bh = *(const short8*)bp;
                short8 bl = *(const short8*)(bp + 512);
                acc[0][t4] = MFMA(ah0, bh, acc[0][t4]);
                acc[0][t4] = MFMA(ah0, bl, acc[0][t4]);
                acc[0][t4] = MFMA(al0, bh, acc[0][t4]);
                acc[1][t4] = MFMA(ah1, bh, acc[1][t4]);
                acc[1][t4] = MFMA(ah1, bl, acc[1][t4]);
                acc[1][t4] = MFMA(al1, bh, acc[1][t4]);
            }
        }
        // ===== layer 0 update =====
        #pragma unroll
        for (int mt = 0; mt < 2; ++mt) {
            #pragma unroll
            for (int r = 0; r < 4; ++r) {
                int m = mt * 16 + l16 * 4 + r;
                float xv = x[t * NSEQ + seq0 + m];
                float gi = acc[mt][0][r] + xv * wih[0] + bb0[0];
                float gf = acc[mt][1][r] + xv * wih[1] + bb0[1];
                float gg = acc[mt][2][r] + xv * wih[2] + bb0[2];
                float go = acc[mt][3][r] + xv * wih[3] + bb0[3];
                float iv = sigf(gi), fv = sigf(gf), gv = tanhf_(gg), ov = sigf(go);
                float c = fv * c0[mt * 4 + r] + iv * gv;
                c0[mt * 4 + r] = c;
                float h = ov * tanhf_(c);
                ushort hh = f2bf(h), hl = f2bf(h - bf2f(hh));
                int ho = nxt * 4096 + (u >> 3) * 256 + m * 8 + (u & 7);
                hA0h[ho] = hh;
                hA0l[ho] = hl;
            }
        }
        __syncthreads();   // new h0 visible

        // ===== layer 1 matmul, pass 1: h0_new @ Wih1 =====
        #pragma unroll
        for (int mt = 0; mt < 2; ++mt)
            #pragma unroll
            for (int t4 = 0; t4 < 4; ++t4) acc[mt][t4] = (f32x4){0.f, 0.f, 0.f, 0.f};
        #pragma unroll
        for (int ks = 0; ks < 4; ++ks) {
            const int a0 = nxt * 4096 + (ks * 4 + l16) * 256 + l15 * 8;   // new h0
            short8 ah0 = *(const short8*)(hA0h + a0);
            short8 al0 = *(const short8*)(hA0l + a0);
            short8 ah1 = *(const short8*)(hA0h + a0 + 128);
            short8 al1 = *(const short8*)(hA0l + a0 + 128);
            #pragma unroll
            for (int t4 = 0; t4 < 4; ++t4) {
                const ushort* bp = WF1i + (size_t)((ks * 32 + t4 * 8 + gr) * 2) * 512 + l * 8;
                short8 bh = *(const short8*)bp;
                short8 bl = *(const short8*)(bp + 512);
                acc[0][t4] = MFMA(ah0, bh, acc[0][t4]);
                acc[0][t4] = MFMA(ah0, bl, acc[0][t4]);
                acc[0][t4] = MFMA(al0, bh, acc[0][t4]);
                acc[1][t4] = MFMA(ah1, bh, acc[1][t4]);
                acc[1][t4] = MFMA(ah1, bl, acc[1][t4]);
                acc[1][t4] = MFMA(al1, bh, acc[1][t4]);
            }
        }
        // ===== layer 1 matmul, pass 2: h1_old @ Whh1 (accumulate) =====
        #pragma unroll
        for (int ks = 0; ks < 4; ++ks) {
            const int a1 = cur * 4096 + (ks * 4 + l16) * 256 + l15 * 8;   // old h1
            short8 ah0 = *(const short8*)(hA1h + a1);
            short8 al0 = *(const short8*)(hA1l + a1);
            short8 ah1 = *(const short8*)(hA1h + a1 + 128);
            short8 al1 = *(const short8*)(hA1l + a1 + 128);
            #pragma unroll
            for (int t4 = 0; t4 < 4; ++t4) {
                const ushort* bp = WF1h + (size_t)((ks * 32 + t4 * 8 + gr) * 2) * 512 + l * 8;
                short8 bh = *(const short8*)bp;
                short8 bl = *(const short8*)(bp + 512);
                acc[0][t4] = MFMA(ah0, bh, acc[0][t4]);
                acc[0][t4] = MFMA(ah0, bl, acc[0][t4]);
                acc[0][t4] = MFMA(al0, bh, acc[0][t4]);
                acc[1][t4] = MFMA(ah1, bh, acc[1][t4]);
                acc[1][t4] = MFMA(ah1, bl, acc[1][t4]);
                acc[1][t4] = MFMA(al1, bh, acc[1][t4]);
            }
        }
        // ===== layer 1 update =====
        #pragma unroll
        for (int mt = 0; mt < 2; ++mt) {
            #pragma unroll
            for (int r = 0; r < 4; ++r) {
                int m = mt * 16 + l16 * 4 + r;
                float gi = acc[mt][0][r] + bb1[0];
                float gf = acc[mt][1][r] + bb1[1];
                float gg = acc[mt][2][r] + bb1[2];
                float go = acc[mt][3][r] + bb1[3];
                float iv = sigf(gi), fv = sigf(gf), gv = tanhf_(gg), ov = sigf(go);
                float c = fv * c1[mt * 4 + r] + iv * gv;
                c1[mt * 4 + r] = c;
                float h = ov * tanhf_(c);
                ushort hh = f2bf(h), hl = f2bf(h - bf2f(hh));
                int ho = nxt * 4096 + (u >> 3) * 256 + m * 8 + (u & 7);
                hA1h[ho] = hh;
                hA1l[ho] = hl;
            }
        }
        __syncthreads();   // new h1 visible
        cur = nxt;
    }

    // ===== FC head =====
    float* hidb = (float*)hA0h;          // overlay: hid [32][33]
    float hv[2];
    #pragma unroll
    for (int r2 = 0; r2 < 2; ++r2) {
        int task = tid + r2 * 512;       // 0..1023 = 32 seq x 32 j
        int s = task >> 5, j = task & 31;
        float sum = fc1_b[j];
        const float* wrow = fc1_w + j * HID;
        #pragma unroll 4
        for (int kq = 0; kq < 16; ++kq) {
            const int off = cur * 4096 + kq * 256 + s * 8;
            short8 H = *(const short8*)(hA1h + off);
            short8 L = *(const short8*)(hA1l + off);
            #pragma unroll
            for (int j8 = 0; j8 < 8; ++j8) {
                float hval = bf2f((ushort)H[j8]) + bf2f((ushort)L[j8]);
                sum += hval * wrow[kq * 8 + j8];
            }
        }
        hv[r2] = fmaxf(sum, 0.f);
    }
    #pragma unroll
    for (int r2 = 0; r2 < 2; ++r2) {
        int task = tid + r2 * 512;
        hidb[(task >> 5) * 33 + (task & 31)] = hv[r2];
    }
    __syncthreads();
    if (tid < SEQB) {
        float sum = fc2_b[0];
        #pragma unroll
        for (int j = 0; j < 32; ++j) sum += hidb[tid * 33 + j] * fc2_w[j];
        out[seq0 + tid] = fmaxf(sum, 0.f);
    }
}

// ---------------------------------------------------------------------------
extern "C" void kernel_launch(void* const* d_in, const int* in_sizes, int n_in,
                              void* d_out, int out_size, void* d_ws, size_t ws_size,
                              hipStream_t stream)
{
    const float* g_data = (const float*)d_in[0];
    const float* weights = (const float*)d_in[1];
    const float* Wih0   = (const float*)d_in[2];
    const float* Whh0   = (const float*)d_in[3];
    const float* bih0   = (const float*)d_in[4];
    const float* bhh0   = (const float*)d_in[5];
    const float* Wih1   = (const float*)d_in[6];
    const float* Whh1   = (const float*)d_in[7];
    const float* bih1   = (const float*)d_in[8];
    const float* bhh1   = (const float*)d_in[9];
    const float* fc1_w  = (const float*)d_in[10];
    const float* fc1_b  = (const float*)d_in[11];
    const float* fc2_w  = (const float*)d_in[12];
    const float* fc2_b  = (const float*)d_in[13];
    float* out = (float*)d_out;

    float* ws = (float*)d_ws;
    float*  x    = ws;                             // 497664 f
    ushort* WF0  = (ushort*)(x + NSEQ * T_STEPS);  // 131072 us
    ushort* WF1i = WF0 + 131072;                   // 131072 us
    ushort* WF1h = WF1i + 131072;                  // 131072 us
    float*  b0p  = (float*)(WF1h + 131072);        // 512 f
    float*  b1p  = b0p + 512;                      // 512 f

    prep_kernel<<<1540, 256, 0, stream>>>(Whh0, Wih1, Whh1, bih0, bhh0, bih1, bhh1,
                                          WF0, WF1i, WF1h, b0p, b1p);
    income_kernel<<<1944, 256, 0, stream>>>(g_data, weights, x);
    lstm_main<<<NSEQ / SEQB, 512, 0, stream>>>(x, WF0, WF1i, WF1h, Wih0, b0p, b1p,
                                               fc1_w, fc1_b, fc2_w, fc2_b, out);
}

// Round 9
// 1517.832 us; speedup vs baseline: 1.0030x; 1.0030x over previous
//
#include <hip/hip_runtime.h>
#include <math.h>

#define NODES 81
#define T_STEPS 12
#define NSEQ 41472
#define HID 128
#define SEQB 32               // sequences per block

typedef unsigned short ushort;
typedef unsigned int uint;
typedef __attribute__((ext_vector_type(8))) short short8;
typedef __attribute__((ext_vector_type(4))) float f32x4;

#define MFMA(A, B, C) __builtin_amdgcn_mfma_f32_16x16x32_bf16((A), (B), (C), 0, 0, 0)

__device__ __forceinline__ ushort f2bf(float v) {
    unsigned int u = __float_as_uint(v);
    unsigned int r = (u + 0x7FFFu + ((u >> 16) & 1u)) >> 16;
    return (ushort)r;
}
__device__ __forceinline__ float bf2f(ushort s) {
    return __uint_as_float(((unsigned int)s) << 16);
}
// fast sigmoid/tanh: v_exp_f32 (2^x) + v_rcp_f32, ~2e-7 rel err
__device__ __forceinline__ float sigf(float v) {
    return __builtin_amdgcn_rcpf(1.f + __builtin_amdgcn_exp2f(v * -1.442695041f));
}
__device__ __forceinline__ float tanhf_(float v) {
    return fmaf(2.f, __builtin_amdgcn_rcpf(1.f + __builtin_amdgcn_exp2f(v * -2.885390082f)), -1.f);
}

// ---------------------------------------------------------------------------
// Prep: MFMA-fragment-major split-bf16 weights, ORIGINAL gate order.
// Layout per matrix: [ks(4)][nt(32)][sel(2)][lane(64)][j(8)] ushort,
// value = W[n*128+k]; k = ks*32 + (lane>>4)*8 + j, n = nt*16 + (lane&15).
// Gate type t, unit-group gr of a tile: nt = t*8 + gr.
// Plus per-unit packed float4 params: wq/b0q/b1q[u*4+t4].
// ---------------------------------------------------------------------------
__global__ void prep_kernel(const float* __restrict__ Whh0,
                            const float* __restrict__ Wih1,
                            const float* __restrict__ Whh1,
                            const float* __restrict__ Wih0,
                            const float* __restrict__ bih0, const float* __restrict__ bhh0,
                            const float* __restrict__ bih1, const float* __restrict__ bhh1,
                            ushort* __restrict__ WF0,
                            ushort* __restrict__ WF1i,
                            ushort* __restrict__ WF1h,
                            float* __restrict__ wq,
                            float* __restrict__ b0q,
                            float* __restrict__ b1q)
{
    int idx = blockIdx.x * 256 + threadIdx.x;   // 394752 total
    if (idx < 393216) {
        int mat = idx >> 17;              // 131072 per matrix
        int li  = idx & 131071;
        int j   = li & 7;
        int l   = (li >> 3) & 63;
        int sel = (li >> 9) & 1;
        int nt  = (li >> 10) & 31;
        int ks  = (li >> 15) & 3;
        int k = ks * 32 + (l >> 4) * 8 + j;
        int n = nt * 16 + (l & 15);
        const float* W = (mat == 0) ? Whh0 : (mat == 1 ? Wih1 : Whh1);
        float v = W[n * 128 + k];
        ushort hs = f2bf(v);
        ushort ov = sel ? f2bf(v - bf2f(hs)) : hs;
        ushort* D = (mat == 0) ? WF0 : (mat == 1 ? WF1i : WF1h);
        D[li] = ov;
    } else if (idx < 393728) {
        int jp = idx - 393216;
        int u = jp >> 2, t4 = jp & 3;
        wq[jp] = Wih0[t4 * 128 + u];
    } else if (idx < 394240) {
        int jp = idx - 393728;
        int u = jp >> 2, t4 = jp & 3;
        b0q[jp] = bih0[t4 * 128 + u] + bhh0[t4 * 128 + u];
    } else {
        int jp = idx - 394240;
        int u = jp >> 2, t4 = jp & 3;
        b1q[jp] = bih1[t4 * 128 + u] + bhh1[t4 * 128 + u];
    }
}

// ---------------------------------------------------------------------------
// income = einsum('bta,an->bnt'); stored t-major: x[t][seq], seq = b*81+n
// ---------------------------------------------------------------------------
__global__ void income_kernel(const float* __restrict__ g_data,
                              const float* __restrict__ w,
                              float* __restrict__ x)
{
    int idx = blockIdx.x * 256 + threadIdx.x;   // 497664 exactly
    int n = idx % NODES;
    int r = idx / NODES;
    int t = r % T_STEPS;
    int b = r / T_STEPS;
    const float* grow = g_data + (b * T_STEPS + t) * NODES;
    float s = 0.f;
    #pragma unroll 3
    for (int a = 0; a < NODES; ++a)
        s += grow[a] * w[a * NODES + n];
    x[t * NSEQ + b * NODES + n] = s;
}

// ---------------------------------------------------------------------------
// Fused 2-layer LSTM + FC head on MFMA (split bf16), transpose-free.
// Block = 32 seqs, 512 threads = 8 waves. Wave gr owns unit-group gr:
// n-tiles {gr, gr+8, gr+16, gr+24} (= i,f,g,o) x 2 m-tiles; lane holds all 4
// gate types of its unit in acc[mt][0..3] -> in-register activation.
// h-state double-buffered in LDS, A-frag layout hA[buf][kq16][m32][j8].
// 2 barriers/step. amdgpu_waves_per_eu(1,2): allow up to 512 VGPR so the
// allocator does NOT clamp to 128 and spill (R6/R7's 627 MB scratch writes).
// ---------------------------------------------------------------------------
__global__ __launch_bounds__(512)
__attribute__((amdgpu_waves_per_eu(1, 2)))
void lstm_main(
    const float* __restrict__ x,        // [12][NSEQ]
    const ushort* __restrict__ WF0,
    const ushort* __restrict__ WF1i,
    const ushort* __restrict__ WF1h,
    const float* __restrict__ wq,       // [128][4] packed per-unit
    const float* __restrict__ b0q,      // [128][4]
    const float* __restrict__ b1q,      // [128][4]
    const float* __restrict__ fc1_w,    // [32][128]
    const float* __restrict__ fc1_b,    // [32]
    const float* __restrict__ fc2_w,    // [32]
    const float* __restrict__ fc2_b,    // [1]
    float* __restrict__ out)            // [NSEQ]
{
    __shared__ __align__(16) ushort hA0h[8192];   // [2][kq16][m32][j8]
    __shared__ __align__(16) ushort hA0l[8192];
    __shared__ __align__(16) ushort hA1h[8192];
    __shared__ __align__(16) ushort hA1l[8192];

    const int tid = threadIdx.x;
    const int l   = tid & 63;
    const int gr  = tid >> 6;          // 0..7 unit-group
    const int l15 = l & 15;
    const int l16 = l >> 4;
    const int u   = gr * 16 + l15;     // owned unit 0..127
    const int seq0 = blockIdx.x * SEQB;

    for (int i = tid; i < 4096; i += 512) {
        ((uint*)hA0h)[i] = 0u; ((uint*)hA0l)[i] = 0u;
        ((uint*)hA1h)[i] = 0u; ((uint*)hA1l)[i] = 0u;
    }

    float c0[8], c1[8];                 // [mt*4+r]
    #pragma unroll
    for (int i = 0; i < 8; ++i) { c0[i] = 0.f; c1[i] = 0.f; }
    __syncthreads();

    int cur = 0;
    for (int t = 0; t < T_STEPS; ++t) {
        const int nxt = cur ^ 1;
        f32x4 acc[2][4];                // [mt][gate-type]

        // ===== layer 0 matmul: h0 @ Whh0 =====
        #pragma unroll
        for (int mt = 0; mt < 2; ++mt)
            #pragma unroll
            for (int t4 = 0; t4 < 4; ++t4) acc[mt][t4] = (f32x4){0.f, 0.f, 0.f, 0.f};
        #pragma unroll
        for (int ks = 0; ks < 4; ++ks) {
            const int ao = cur * 4096 + (ks * 4 + l16) * 256 + l15 * 8;
            short8 ah0 = *(const short8*)(hA0h + ao);
            short8 al0 = *(const short8*)(hA0l + ao);
            short8 ah1 = *(const short8*)(hA0h + ao + 128);
            short8 al1 = *(const short8*)(hA0l + ao + 128);
            #pragma unroll
            for (int t4 = 0; t4 < 4; ++t4) {
                const ushort* bp = WF0 + (size_t)((ks * 32 + t4 * 8 + gr) * 2) * 512 + l * 8;
                short8 bh = *(const short8*)bp;
                short8 bl = *(const short8*)(bp + 512);
                acc[0][t4] = MFMA(ah0, bh, acc[0][t4]);
                acc[0][t4] = MFMA(ah0, bl, acc[0][t4]);
                acc[0][t4] = MFMA(al0, bh, acc[0][t4]);
                acc[1][t4] = MFMA(ah1, bh, acc[1][t4]);
                acc[1][t4] = MFMA(ah1, bl, acc[1][t4]);
                acc[1][t4] = MFMA(al1, bh, acc[1][t4]);
            }
        }
        // ===== layer 0 update =====
        {
            float4 wv  = *(const float4*)(wq  + u * 4);
            float4 bv0 = *(const float4*)(b0q + u * 4);
            #pragma unroll
            for (int mt = 0; mt < 2; ++mt) {
                #pragma unroll
                for (int r = 0; r < 4; ++r) {
                    int m = mt * 16 + l16 * 4 + r;
                    float xv = x[t * NSEQ + seq0 + m];
                    float gi = acc[mt][0][r] + xv * wv.x + bv0.x;
                    float gf = acc[mt][1][r] + xv * wv.y + bv0.y;
                    float gg = acc[mt][2][r] + xv * wv.z + bv0.z;
                    float go = acc[mt][3][r] + xv * wv.w + bv0.w;
                    float iv = sigf(gi), fv = sigf(gf), gv = tanhf_(gg), ov = sigf(go);
                    float c = fv * c0[mt * 4 + r] + iv * gv;
                    c0[mt * 4 + r] = c;
                    float h = ov * tanhf_(c);
                    ushort hh = f2bf(h), hl = f2bf(h - bf2f(hh));
                    int ho = nxt * 4096 + (u >> 3) * 256 + m * 8 + (u & 7);
                    hA0h[ho] = hh;
                    hA0l[ho] = hl;
                }
            }
        }
        __syncthreads();   // new h0 visible

        // ===== layer 1 matmul, pass 1: h0_new @ Wih1 =====
        #pragma unroll
        for (int mt = 0; mt < 2; ++mt)
            #pragma unroll
            for (int t4 = 0; t4 < 4; ++t4) acc[mt][t4] = (f32x4){0.f, 0.f, 0.f, 0.f};
        #pragma unroll
        for (int ks = 0; ks < 4; ++ks) {
            const int a0 = nxt * 4096 + (ks * 4 + l16) * 256 + l15 * 8;   // new h0
            short8 ah0 = *(const short8*)(hA0h + a0);
            short8 al0 = *(const short8*)(hA0l + a0);
            short8 ah1 = *(const short8*)(hA0h + a0 + 128);
            short8 al1 = *(const short8*)(hA0l + a0 + 128);
            #pragma unroll
            for (int t4 = 0; t4 < 4; ++t4) {
                const ushort* bp = WF1i + (size_t)((ks * 32 + t4 * 8 + gr) * 2) * 512 + l * 8;
                short8 bh = *(const short8*)bp;
                short8 bl = *(const short8*)(bp + 512);
                acc[0][t4] = MFMA(ah0, bh, acc[0][t4]);
                acc[0][t4] = MFMA(ah0, bl, acc[0][t4]);
                acc[0][t4] = MFMA(al0, bh, acc[0][t4]);
                acc[1][t4] = MFMA(ah1, bh, acc[1][t4]);
                acc[1][t4] = MFMA(ah1, bl, acc[1][t4]);
                acc[1][t4] = MFMA(al1, bh, acc[1][t4]);
            }
        }
        // ===== layer 1 matmul, pass 2: h1_old @ Whh1 (accumulate) =====
        #pragma unroll
        for (int ks = 0; ks < 4; ++ks) {
            const int a1 = cur * 4096 + (ks * 4 + l16) * 256 + l15 * 8;   // old h1
            short8 ah0 = *(const short8*)(hA1h + a1);
            short8 al0 = *(const short8*)(hA1l + a1);
            short8 ah1 = *(const short8*)(hA1h + a1 + 128);
            short8 al1 = *(const short8*)(hA1l + a1 + 128);
            #pragma unroll
            for (int t4 = 0; t4 < 4; ++t4) {
                const ushort* bp = WF1h + (size_t)((ks * 32 + t4 * 8 + gr) * 2) * 512 + l * 8;
                short8 bh = *(const short8*)bp;
                short8 bl = *(const short8*)(bp + 512);
                acc[0][t4] = MFMA(ah0, bh, acc[0][t4]);
                acc[0][t4] = MFMA(ah0, bl, acc[0][t4]);
                acc[0][t4] = MFMA(al0, bh, acc[0][t4]);
                acc[1][t4] = MFMA(ah1, bh, acc[1][t4]);
                acc[1][t4] = MFMA(ah1, bl, acc[1][t4]);
                acc[1][t4] = MFMA(al1, bh, acc[1][t4]);
            }
        }
        // ===== layer 1 update =====
        {
            float4 bv1 = *(const float4*)(b1q + u * 4);
            #pragma unroll
            for (int mt = 0; mt < 2; ++mt) {
                #pragma unroll
                for (int r = 0; r < 4; ++r) {
                    int m = mt * 16 + l16 * 4 + r;
                    float gi = acc[mt][0][r] + bv1.x;
                    float gf = acc[mt][1][r] + bv1.y;
                    float gg = acc[mt][2][r] + bv1.z;
                    float go = acc[mt][3][r] + bv1.w;
                    float iv = sigf(gi), fv = sigf(gf), gv = tanhf_(gg), ov = sigf(go);
                    float c = fv * c1[mt * 4 + r] + iv * gv;
                    c1[mt * 4 + r] = c;
                    float h = ov * tanhf_(c);
                    ushort hh = f2bf(h), hl = f2bf(h - bf2f(hh));
                    int ho = nxt * 4096 + (u >> 3) * 256 + m * 8 + (u & 7);
                    hA1h[ho] = hh;
                    hA1l[ho] = hl;
                }
            }
        }
        __syncthreads();   // new h1 visible
        cur = nxt;
    }

    // ===== FC head =====
    float* hidb = (float*)hA0h;          // overlay: hid [32][33]
    float hv[2];
    #pragma unroll
    for (int r2 = 0; r2 < 2; ++r2) {
        int task = tid + r2 * 512;       // 0..1023 = 32 seq x 32 j
        int s = task >> 5, j = task & 31;
        float sum = fc1_b[j];
        const float* wrow = fc1_w + j * HID;
        #pragma unroll 4
        for (int kq = 0; kq < 16; ++kq) {
            const int off = cur * 4096 + kq * 256 + s * 8;
            short8 H = *(const short8*)(hA1h + off);
            short8 L = *(const short8*)(hA1l + off);
            #pragma unroll
            for (int j8 = 0; j8 < 8; ++j8) {
                float hval = bf2f((ushort)H[j8]) + bf2f((ushort)L[j8]);
                sum += hval * wrow[kq * 8 + j8];
            }
        }
        hv[r2] = fmaxf(sum, 0.f);
    }
    #pragma unroll
    for (int r2 = 0; r2 < 2; ++r2) {
        int task = tid + r2 * 512;
        hidb[(task >> 5) * 33 + (task & 31)] = hv[r2];
    }
    __syncthreads();
    if (tid < SEQB) {
        float sum = fc2_b[0];
        #pragma unroll
        for (int j = 0; j < 32; ++j) sum += hidb[tid * 33 + j] * fc2_w[j];
        out[seq0 + tid] = fmaxf(sum, 0.f);
    }
}

// ---------------------------------------------------------------------------
extern "C" void kernel_launch(void* const* d_in, const int* in_sizes, int n_in,
                              void* d_out, int out_size, void* d_ws, size_t ws_size,
                              hipStream_t stream)
{
    const float* g_data = (const float*)d_in[0];
    const float* weights = (const float*)d_in[1];
    const float* Wih0   = (const float*)d_in[2];
    const float* Whh0   = (const float*)d_in[3];
    const float* bih0   = (const float*)d_in[4];
    const float* bhh0   = (const float*)d_in[5];
    const float* Wih1   = (const float*)d_in[6];
    const float* Whh1   = (const float*)d_in[7];
    const float* bih1   = (const float*)d_in[8];
    const float* bhh1   = (const float*)d_in[9];
    const float* fc1_w  = (const float*)d_in[10];
    const float* fc1_b  = (const float*)d_in[11];
    const float* fc2_w  = (const float*)d_in[12];
    const float* fc2_b  = (const float*)d_in[13];
    float* out = (float*)d_out;

    float* ws = (float*)d_ws;
    float*  x    = ws;                             // 497664 f
    ushort* WF0  = (ushort*)(x + NSEQ * T_STEPS);  // 131072 us
    ushort* WF1i = WF0 + 131072;                   // 131072 us
    ushort* WF1h = WF1i + 131072;                  // 131072 us
    float*  wqp  = (float*)(WF1h + 131072);        // 512 f
    float*  b0q  = wqp + 512;                      // 512 f
    float*  b1q  = b0q + 512;                      // 512 f

    prep_kernel<<<1542, 256, 0, stream>>>(Whh0, Wih1, Whh1, Wih0, bih0, bhh0, bih1, bhh1,
                                          WF0, WF1i, WF1h, wqp, b0q, b1q);
    income_kernel<<<1944, 256, 0, stream>>>(g_data, weights, x);
    lstm_main<<<NSEQ / SEQB, 512, 0, stream>>>(x, WF0, WF1i, WF1h, wqp, b0q, b1q,
                                               fc1_w, fc1_b, fc2_w, fc2_b, out);
}

// Round 10
// 695.342 us; speedup vs baseline: 2.1895x; 2.1829x over previous
//
#include <hip/hip_runtime.h>
#include <math.h>

#define NODES 81
#define T_STEPS 12
#define NSEQ 41472
#define HID 128
#define SEQB 32               // sequences per block

typedef unsigned short ushort;
typedef unsigned int uint;
typedef __attribute__((ext_vector_type(8))) short short8;
typedef __attribute__((ext_vector_type(4))) float f32x4;

#define MFMA(A, B, C) __builtin_amdgcn_mfma_f32_16x16x32_bf16((A), (B), (C), 0, 0, 0)

__device__ __forceinline__ ushort f2bf(float v) {
    unsigned int u = __float_as_uint(v);
    unsigned int r = (u + 0x7FFFu + ((u >> 16) & 1u)) >> 16;
    return (ushort)r;
}
__device__ __forceinline__ float bf2f(ushort s) {
    return __uint_as_float(((unsigned int)s) << 16);
}
// fast sigmoid/tanh: v_exp_f32 (2^x) + v_rcp_f32, ~2e-7 rel err
__device__ __forceinline__ float sigf(float v) {
    return __builtin_amdgcn_rcpf(1.f + __builtin_amdgcn_exp2f(v * -1.442695041f));
}
__device__ __forceinline__ float tanhf_(float v) {
    return fmaf(2.f, __builtin_amdgcn_rcpf(1.f + __builtin_amdgcn_exp2f(v * -2.885390082f)), -1.f);
}

// ---------------------------------------------------------------------------
// Prep: MFMA-fragment-major split-bf16 weights, ORIGINAL gate order.
// Layout per matrix: [ks(4)][nt(32)][sel(2)][lane(64)][j(8)] ushort,
// value = W[n*128+k]; k = ks*32 + (lane>>4)*8 + j, n = nt*16 + (lane&15).
// Gate type t, unit-group gr of a tile: nt = t*8 + gr.
// Plus per-unit packed float4 params: wq/b0q/b1q[u*4+t4].
// ---------------------------------------------------------------------------
__global__ void prep_kernel(const float* __restrict__ Whh0,
                            const float* __restrict__ Wih1,
                            const float* __restrict__ Whh1,
                            const float* __restrict__ Wih0,
                            const float* __restrict__ bih0, const float* __restrict__ bhh0,
                            const float* __restrict__ bih1, const float* __restrict__ bhh1,
                            ushort* __restrict__ WF0,
                            ushort* __restrict__ WF1i,
                            ushort* __restrict__ WF1h,
                            float* __restrict__ wq,
                            float* __restrict__ b0q,
                            float* __restrict__ b1q)
{
    int idx = blockIdx.x * 256 + threadIdx.x;   // 394752 total
    if (idx < 393216) {
        int mat = idx >> 17;              // 131072 per matrix
        int li  = idx & 131071;
        int j   = li & 7;
        int l   = (li >> 3) & 63;
        int sel = (li >> 9) & 1;
        int nt  = (li >> 10) & 31;
        int ks  = (li >> 15) & 3;
        int k = ks * 32 + (l >> 4) * 8 + j;
        int n = nt * 16 + (l & 15);
        const float* W = (mat == 0) ? Whh0 : (mat == 1 ? Wih1 : Whh1);
        float v = W[n * 128 + k];
        ushort hs = f2bf(v);
        ushort ov = sel ? f2bf(v - bf2f(hs)) : hs;
        ushort* D = (mat == 0) ? WF0 : (mat == 1 ? WF1i : WF1h);
        D[li] = ov;
    } else if (idx < 393728) {
        int jp = idx - 393216;
        int u = jp >> 2, t4 = jp & 3;
        wq[jp] = Wih0[t4 * 128 + u];
    } else if (idx < 394240) {
        int jp = idx - 393728;
        int u = jp >> 2, t4 = jp & 3;
        b0q[jp] = bih0[t4 * 128 + u] + bhh0[t4 * 128 + u];
    } else {
        int jp = idx - 394240;
        int u = jp >> 2, t4 = jp & 3;
        b1q[jp] = bih1[t4 * 128 + u] + bhh1[t4 * 128 + u];
    }
}

// ---------------------------------------------------------------------------
// income = einsum('bta,an->bnt'); stored t-major: x[t][seq], seq = b*81+n
// ---------------------------------------------------------------------------
__global__ void income_kernel(const float* __restrict__ g_data,
                              const float* __restrict__ w,
                              float* __restrict__ x)
{
    int idx = blockIdx.x * 256 + threadIdx.x;   // 497664 exactly
    int n = idx % NODES;
    int r = idx / NODES;
    int t = r % T_STEPS;
    int b = r / T_STEPS;
    const float* grow = g_data + (b * T_STEPS + t) * NODES;
    float s = 0.f;
    #pragma unroll 3
    for (int a = 0; a < NODES; ++a)
        s += grow[a] * w[a * NODES + n];
    x[t * NSEQ + b * NODES + n] = s;
}

// ---------------------------------------------------------------------------
// Fused 2-layer LSTM + FC head on MFMA (split bf16), transpose-free.
// Block = 32 seqs, 512 threads = 8 waves. Wave gr owns unit-group gr:
// n-tiles {gr, gr+8, gr+16, gr+24} (= i,f,g,o) x 2 m-tiles; lane holds all 4
// gate types of its unit in acc[mt][0..3] -> in-register activation.
// h-state double-buffered in LDS, A-frag layout hA[buf][kq16][m32][j8].
// 2 barriers/step.
// KEY (R9): #pragma unroll 1 on the ks loops. Full unroll let the scheduler
// hoist ~32 in-flight short8 weight loads (~128 VGPR), blowing the 128-VGPR
// budget -> 632 MB scratch writes + 3.7 GB L2-thrash fetch (R6-R8 counters).
// Per-iteration working set now: 16 A + 32 B + acc -> fits, no spill.
// ---------------------------------------------------------------------------
__global__ __launch_bounds__(512, 1) void lstm_main(
    const float* __restrict__ x,        // [12][NSEQ]
    const ushort* __restrict__ WF0,
    const ushort* __restrict__ WF1i,
    const ushort* __restrict__ WF1h,
    const float* __restrict__ wq,       // [128][4] packed per-unit
    const float* __restrict__ b0q,      // [128][4]
    const float* __restrict__ b1q,      // [128][4]
    const float* __restrict__ fc1_w,    // [32][128]
    const float* __restrict__ fc1_b,    // [32]
    const float* __restrict__ fc2_w,    // [32]
    const float* __restrict__ fc2_b,    // [1]
    float* __restrict__ out)            // [NSEQ]
{
    __shared__ __align__(16) ushort hA0h[8192];   // [2][kq16][m32][j8]
    __shared__ __align__(16) ushort hA0l[8192];
    __shared__ __align__(16) ushort hA1h[8192];
    __shared__ __align__(16) ushort hA1l[8192];

    const int tid = threadIdx.x;
    const int l   = tid & 63;
    const int gr  = tid >> 6;          // 0..7 unit-group
    const int l15 = l & 15;
    const int l16 = l >> 4;
    const int u   = gr * 16 + l15;     // owned unit 0..127
    const int seq0 = blockIdx.x * SEQB;

    for (int i = tid; i < 4096; i += 512) {
        ((uint*)hA0h)[i] = 0u; ((uint*)hA0l)[i] = 0u;
        ((uint*)hA1h)[i] = 0u; ((uint*)hA1l)[i] = 0u;
    }

    float c0[8], c1[8];                 // [mt*4+r]
    #pragma unroll
    for (int i = 0; i < 8; ++i) { c0[i] = 0.f; c1[i] = 0.f; }
    __syncthreads();

    int cur = 0;
    for (int t = 0; t < T_STEPS; ++t) {
        const int nxt = cur ^ 1;
        f32x4 acc[2][4];                // [mt][gate-type]

        // ===== layer 0 matmul: h0 @ Whh0 =====
        #pragma unroll
        for (int mt = 0; mt < 2; ++mt)
            #pragma unroll
            for (int t4 = 0; t4 < 4; ++t4) acc[mt][t4] = (f32x4){0.f, 0.f, 0.f, 0.f};
        #pragma unroll 1
        for (int ks = 0; ks < 4; ++ks) {
            const int ao = cur * 4096 + (ks * 4 + l16) * 256 + l15 * 8;
            short8 ah0 = *(const short8*)(hA0h + ao);
            short8 al0 = *(const short8*)(hA0l + ao);
            short8 ah1 = *(const short8*)(hA0h + ao + 128);
            short8 al1 = *(const short8*)(hA0l + ao + 128);
            #pragma unroll
            for (int t4 = 0; t4 < 4; ++t4) {
                const ushort* bp = WF0 + (size_t)((ks * 32 + t4 * 8 + gr) * 2) * 512 + l * 8;
                short8 bh = *(const short8*)bp;
                short8 bl = *(const short8*)(bp + 512);
                acc[0][t4] = MFMA(ah0, bh, acc[0][t4]);
                acc[0][t4] = MFMA(ah0, bl, acc[0][t4]);
                acc[0][t4] = MFMA(al0, bh, acc[0][t4]);
                acc[1][t4] = MFMA(ah1, bh, acc[1][t4]);
                acc[1][t4] = MFMA(ah1, bl, acc[1][t4]);
                acc[1][t4] = MFMA(al1, bh, acc[1][t4]);
            }
        }
        // ===== layer 0 update =====
        {
            float4 wv  = *(const float4*)(wq  + u * 4);
            float4 bv0 = *(const float4*)(b0q + u * 4);
            #pragma unroll
            for (int mt = 0; mt < 2; ++mt) {
                #pragma unroll
                for (int r = 0; r < 4; ++r) {
                    int m = mt * 16 + l16 * 4 + r;
                    float xv = x[t * NSEQ + seq0 + m];
                    float gi = acc[mt][0][r] + xv * wv.x + bv0.x;
                    float gf = acc[mt][1][r] + xv * wv.y + bv0.y;
                    float gg = acc[mt][2][r] + xv * wv.z + bv0.z;
                    float go = acc[mt][3][r] + xv * wv.w + bv0.w;
                    float iv = sigf(gi), fv = sigf(gf), gv = tanhf_(gg), ov = sigf(go);
                    float c = fv * c0[mt * 4 + r] + iv * gv;
                    c0[mt * 4 + r] = c;
                    float h = ov * tanhf_(c);
                    ushort hh = f2bf(h), hl = f2bf(h - bf2f(hh));
                    int ho = nxt * 4096 + (u >> 3) * 256 + m * 8 + (u & 7);
                    hA0h[ho] = hh;
                    hA0l[ho] = hl;
                }
            }
        }
        __syncthreads();   // new h0 visible

        // ===== layer 1 matmul, pass 1: h0_new @ Wih1 =====
        #pragma unroll
        for (int mt = 0; mt < 2; ++mt)
            #pragma unroll
            for (int t4 = 0; t4 < 4; ++t4) acc[mt][t4] = (f32x4){0.f, 0.f, 0.f, 0.f};
        #pragma unroll 1
        for (int ks = 0; ks < 4; ++ks) {
            const int a0 = nxt * 4096 + (ks * 4 + l16) * 256 + l15 * 8;   // new h0
            short8 ah0 = *(const short8*)(hA0h + a0);
            short8 al0 = *(const short8*)(hA0l + a0);
            short8 ah1 = *(const short8*)(hA0h + a0 + 128);
            short8 al1 = *(const short8*)(hA0l + a0 + 128);
            #pragma unroll
            for (int t4 = 0; t4 < 4; ++t4) {
                const ushort* bp = WF1i + (size_t)((ks * 32 + t4 * 8 + gr) * 2) * 512 + l * 8;
                short8 bh = *(const short8*)bp;
                short8 bl = *(const short8*)(bp + 512);
                acc[0][t4] = MFMA(ah0, bh, acc[0][t4]);
                acc[0][t4] = MFMA(ah0, bl, acc[0][t4]);
                acc[0][t4] = MFMA(al0, bh, acc[0][t4]);
                acc[1][t4] = MFMA(ah1, bh, acc[1][t4]);
                acc[1][t4] = MFMA(ah1, bl, acc[1][t4]);
                acc[1][t4] = MFMA(al1, bh, acc[1][t4]);
            }
        }
        // ===== layer 1 matmul, pass 2: h1_old @ Whh1 (accumulate) =====
        #pragma unroll 1
        for (int ks = 0; ks < 4; ++ks) {
            const int a1 = cur * 4096 + (ks * 4 + l16) * 256 + l15 * 8;   // old h1
            short8 ah0 = *(const short8*)(hA1h + a1);
            short8 al0 = *(const short8*)(hA1l + a1);
            short8 ah1 = *(const short8*)(hA1h + a1 + 128);
            short8 al1 = *(const short8*)(hA1l + a1 + 128);
            #pragma unroll
            for (int t4 = 0; t4 < 4; ++t4) {
                const ushort* bp = WF1h + (size_t)((ks * 32 + t4 * 8 + gr) * 2) * 512 + l * 8;
                short8 bh = *(const short8*)bp;
                short8 bl = *(const short8*)(bp + 512);
                acc[0][t4] = MFMA(ah0, bh, acc[0][t4]);
                acc[0][t4] = MFMA(ah0, bl, acc[0][t4]);
                acc[0][t4] = MFMA(al0, bh, acc[0][t4]);
                acc[1][t4] = MFMA(ah1, bh, acc[1][t4]);
                acc[1][t4] = MFMA(ah1, bl, acc[1][t4]);
                acc[1][t4] = MFMA(al1, bh, acc[1][t4]);
            }
        }
        // ===== layer 1 update =====
        {
            float4 bv1 = *(const float4*)(b1q + u * 4);
            #pragma unroll
            for (int mt = 0; mt < 2; ++mt) {
                #pragma unroll
                for (int r = 0; r < 4; ++r) {
                    int m = mt * 16 + l16 * 4 + r;
                    float gi = acc[mt][0][r] + bv1.x;
                    float gf = acc[mt][1][r] + bv1.y;
                    float gg = acc[mt][2][r] + bv1.z;
                    float go = acc[mt][3][r] + bv1.w;
                    float iv = sigf(gi), fv = sigf(gf), gv = tanhf_(gg), ov = sigf(go);
                    float c = fv * c1[mt * 4 + r] + iv * gv;
                    c1[mt * 4 + r] = c;
                    float h = ov * tanhf_(c);
                    ushort hh = f2bf(h), hl = f2bf(h - bf2f(hh));
                    int ho = nxt * 4096 + (u >> 3) * 256 + m * 8 + (u & 7);
                    hA1h[ho] = hh;
                    hA1l[ho] = hl;
                }
            }
        }
        __syncthreads();   // new h1 visible
        cur = nxt;
    }

    // ===== FC head =====
    float* hidb = (float*)hA0h;          // overlay: hid [32][33]
    float hv[2];
    #pragma unroll
    for (int r2 = 0; r2 < 2; ++r2) {
        int task = tid + r2 * 512;       // 0..1023 = 32 seq x 32 j
        int s = task >> 5, j = task & 31;
        float sum = fc1_b[j];
        const float* wrow = fc1_w + j * HID;
        #pragma unroll 4
        for (int kq = 0; kq < 16; ++kq) {
            const int off = cur * 4096 + kq * 256 + s * 8;
            short8 H = *(const short8*)(hA1h + off);
            short8 L = *(const short8*)(hA1l + off);
            #pragma unroll
            for (int j8 = 0; j8 < 8; ++j8) {
                float hval = bf2f((ushort)H[j8]) + bf2f((ushort)L[j8]);
                sum += hval * wrow[kq * 8 + j8];
            }
        }
        hv[r2] = fmaxf(sum, 0.f);
    }
    #pragma unroll
    for (int r2 = 0; r2 < 2; ++r2) {
        int task = tid + r2 * 512;
        hidb[(task >> 5) * 33 + (task & 31)] = hv[r2];
    }
    __syncthreads();
    if (tid < SEQB) {
        float sum = fc2_b[0];
        #pragma unroll
        for (int j = 0; j < 32; ++j) sum += hidb[tid * 33 + j] * fc2_w[j];
        out[seq0 + tid] = fmaxf(sum, 0.f);
    }
}

// ---------------------------------------------------------------------------
extern "C" void kernel_launch(void* const* d_in, const int* in_sizes, int n_in,
                              void* d_out, int out_size, void* d_ws, size_t ws_size,
                              hipStream_t stream)
{
    const float* g_data = (const float*)d_in[0];
    const float* weights = (const float*)d_in[1];
    const float* Wih0   = (const float*)d_in[2];
    const float* Whh0   = (const float*)d_in[3];
    const float* bih0   = (const float*)d_in[4];
    const float* bhh0   = (const float*)d_in[5];
    const float* Wih1   = (const float*)d_in[6];
    const float* Whh1   = (const float*)d_in[7];
    const float* bih1   = (const float*)d_in[8];
    const float* bhh1   = (const float*)d_in[9];
    const float* fc1_w  = (const float*)d_in[10];
    const float* fc1_b  = (const float*)d_in[11];
    const float* fc2_w  = (const float*)d_in[12];
    const float* fc2_b  = (const float*)d_in[13];
    float* out = (float*)d_out;

    float* ws = (float*)d_ws;
    float*  x    = ws;                             // 497664 f
    ushort* WF0  = (ushort*)(x + NSEQ * T_STEPS);  // 131072 us
    ushort* WF1i = WF0 + 131072;                   // 131072 us
    ushort* WF1h = WF1i + 131072;                  // 131072 us
    float*  wqp  = (float*)(WF1h + 131072);        // 512 f
    float*  b0q  = wqp + 512;                      // 512 f
    float*  b1q  = b0q + 512;                      // 512 f

    prep_kernel<<<1542, 256, 0, stream>>>(Whh0, Wih1, Whh1, Wih0, bih0, bhh0, bih1, bhh1,
                                          WF0, WF1i, WF1h, wqp, b0q, b1q);
    income_kernel<<<1944, 256, 0, stream>>>(g_data, weights, x);
    lstm_main<<<NSEQ / SEQB, 512, 0, stream>>>(x, WF0, WF1i, WF1h, wqp, b0q, b1q,
                                               fc1_w, fc1_b, fc2_w, fc2_b, out);
}

// Round 11
// 438.748 us; speedup vs baseline: 3.4700x; 1.5848x over previous
//
#include <hip/hip_runtime.h>
#include <math.h>

#define NODES 81
#define T_STEPS 12
#define NSEQ 41472
#define HID 128
#define SEQB 32               // sequences per block

typedef unsigned short ushort;
typedef unsigned int uint;
typedef __attribute__((ext_vector_type(8))) _Float16 half8;
typedef __attribute__((ext_vector_type(4))) float f32x4;

#define MFMA(A, B, C) __builtin_amdgcn_mfma_f32_16x16x32_f16((A), (B), (C), 0, 0, 0)

// fast sigmoid/tanh: v_exp_f32 (2^x) + v_rcp_f32, ~2e-7 rel err
__device__ __forceinline__ float sigf(float v) {
    return __builtin_amdgcn_rcpf(1.f + __builtin_amdgcn_exp2f(v * -1.442695041f));
}
__device__ __forceinline__ float tanhf_(float v) {
    return fmaf(2.f, __builtin_amdgcn_rcpf(1.f + __builtin_amdgcn_exp2f(v * -2.885390082f)), -1.f);
}

// ---------------------------------------------------------------------------
// Prep: MFMA-fragment-major fp16 weights, ORIGINAL gate order.
// Layout per matrix: [ks(4)][nt(32)][lane(64)][j(8)] _Float16,
// value = W[n*128+k]; k = ks*32 + (lane>>4)*8 + j, n = nt*16 + (lane&15).
// Gate type t4, unit-group gr of a tile: nt = t4*8 + gr.
// Plus per-unit packed float4 params: wq/b0q/b1q[u*4+t4] (fp32, exact).
// ---------------------------------------------------------------------------
__global__ void prep_kernel(const float* __restrict__ Whh0,
                            const float* __restrict__ Wih1,
                            const float* __restrict__ Whh1,
                            const float* __restrict__ Wih0,
                            const float* __restrict__ bih0, const float* __restrict__ bhh0,
                            const float* __restrict__ bih1, const float* __restrict__ bhh1,
                            _Float16* __restrict__ WF0,
                            _Float16* __restrict__ WF1i,
                            _Float16* __restrict__ WF1h,
                            float* __restrict__ wq,
                            float* __restrict__ b0q,
                            float* __restrict__ b1q)
{
    int idx = blockIdx.x * 256 + threadIdx.x;   // 198144 total, exact
    if (idx < 196608) {
        int mat = idx >> 16;              // 65536 per matrix
        int li  = idx & 65535;
        int j   = li & 7;
        int l   = (li >> 3) & 63;
        int nt  = (li >> 9) & 31;
        int ks  = li >> 14;
        int k = ks * 32 + (l >> 4) * 8 + j;
        int n = nt * 16 + (l & 15);
        const float* W = (mat == 0) ? Whh0 : (mat == 1 ? Wih1 : Whh1);
        _Float16* D = (mat == 0) ? WF0 : (mat == 1 ? WF1i : WF1h);
        D[li] = (_Float16)W[n * 128 + k];
    } else if (idx < 197120) {
        int jp = idx - 196608;
        int u = jp >> 2, t4 = jp & 3;
        wq[jp] = Wih0[t4 * 128 + u];
    } else if (idx < 197632) {
        int jp = idx - 197120;
        int u = jp >> 2, t4 = jp & 3;
        b0q[jp] = bih0[t4 * 128 + u] + bhh0[t4 * 128 + u];
    } else if (idx < 198144) {
        int jp = idx - 197632;
        int u = jp >> 2, t4 = jp & 3;
        b1q[jp] = bih1[t4 * 128 + u] + bhh1[t4 * 128 + u];
    }
}

// ---------------------------------------------------------------------------
// income = einsum('bta,an->bnt'); stored t-major: x[t][seq], seq = b*81+n
// ---------------------------------------------------------------------------
__global__ void income_kernel(const float* __restrict__ g_data,
                              const float* __restrict__ w,
                              float* __restrict__ x)
{
    int idx = blockIdx.x * 256 + threadIdx.x;   // 497664 exactly
    int n = idx % NODES;
    int r = idx / NODES;
    int t = r % T_STEPS;
    int b = r / T_STEPS;
    const float* grow = g_data + (b * T_STEPS + t) * NODES;
    float s = 0.f;
    #pragma unroll 3
    for (int a = 0; a < NODES; ++a)
        s += grow[a] * w[a * NODES + n];
    x[t * NSEQ + b * NODES + n] = s;
}

// ---------------------------------------------------------------------------
// Fused 2-layer LSTM + FC head on fp16 MFMA (single term: 11-bit mantissa).
// Block = 32 seqs, 512 threads = 8 waves. Wave gr owns unit-group gr:
// n-tiles {gr, gr+8, gr+16, gr+24} (= i,f,g,o) x 2 m-tiles; lane holds all 4
// gate types of its unit in acc[mt][0..3] -> in-register activation.
// h-state double-buffered fp16 in LDS, A-frag layout hA[buf][kq16][m32][j8].
// 2 barriers/step. LDS 32 KB. ks loops stay unroll-1 (R9 anti-spill lesson).
// ---------------------------------------------------------------------------
__global__ __launch_bounds__(512, 1) void lstm_main(
    const float* __restrict__ x,        // [12][NSEQ]
    const _Float16* __restrict__ WF0,
    const _Float16* __restrict__ WF1i,
    const _Float16* __restrict__ WF1h,
    const float* __restrict__ wq,       // [128][4] packed per-unit
    const float* __restrict__ b0q,      // [128][4]
    const float* __restrict__ b1q,      // [128][4]
    const float* __restrict__ fc1_w,    // [32][128]
    const float* __restrict__ fc1_b,    // [32]
    const float* __restrict__ fc2_w,    // [32]
    const float* __restrict__ fc2_b,    // [1]
    float* __restrict__ out)            // [NSEQ]
{
    __shared__ __align__(16) _Float16 hA0[8192];   // [2][kq16][m32][j8]
    __shared__ __align__(16) _Float16 hA1[8192];

    const int tid = threadIdx.x;
    const int l   = tid & 63;
    const int gr  = tid >> 6;          // 0..7 unit-group
    const int l15 = l & 15;
    const int l16 = l >> 4;
    const int u   = gr * 16 + l15;     // owned unit 0..127
    const int seq0 = blockIdx.x * SEQB;

    for (int i = tid; i < 4096; i += 512) {
        ((uint*)hA0)[i] = 0u; ((uint*)hA1)[i] = 0u;
    }

    // wave/lane-invariant B bases (fragment index = ks*16384 + t4*4096 + gr*512 + l*8)
    const _Float16* wfb0 = WF0  + gr * 512 + l * 8;
    const _Float16* wfb1 = WF1i + gr * 512 + l * 8;
    const _Float16* wfb2 = WF1h + gr * 512 + l * 8;

    float c0[8], c1[8];                 // [mt*4+r]
    #pragma unroll
    for (int i = 0; i < 8; ++i) { c0[i] = 0.f; c1[i] = 0.f; }
    __syncthreads();

    int cur = 0;
    for (int t = 0; t < T_STEPS; ++t) {
        const int nxt = cur ^ 1;
        const float* xb = x + t * NSEQ + seq0;
        f32x4 acc[2][4];                // [mt][gate-type]

        // ===== layer 0 matmul: h0 @ Whh0 =====
        #pragma unroll
        for (int mt = 0; mt < 2; ++mt)
            #pragma unroll
            for (int t4 = 0; t4 < 4; ++t4) acc[mt][t4] = (f32x4){0.f, 0.f, 0.f, 0.f};
        #pragma unroll 1
        for (int ks = 0; ks < 4; ++ks) {
            const int ao = cur * 4096 + (ks * 4 + l16) * 256 + l15 * 8;
            half8 a0 = *(const half8*)(hA0 + ao);
            half8 a1 = *(const half8*)(hA0 + ao + 128);
            #pragma unroll
            for (int t4 = 0; t4 < 4; ++t4) {
                half8 b = *(const half8*)(wfb0 + ks * 16384 + t4 * 4096);
                acc[0][t4] = MFMA(a0, b, acc[0][t4]);
                acc[1][t4] = MFMA(a1, b, acc[1][t4]);
            }
        }
        // ===== layer 0 update (in-register activation) =====
        {
            float4 wv  = *(const float4*)(wq  + u * 4);
            float4 bv0 = *(const float4*)(b0q + u * 4);
            #pragma unroll
            for (int mt = 0; mt < 2; ++mt) {
                #pragma unroll
                for (int r = 0; r < 4; ++r) {
                    int m = mt * 16 + l16 * 4 + r;
                    float xv = xb[m];
                    float gi = acc[mt][0][r] + xv * wv.x + bv0.x;
                    float gf = acc[mt][1][r] + xv * wv.y + bv0.y;
                    float gg = acc[mt][2][r] + xv * wv.z + bv0.z;
                    float go = acc[mt][3][r] + xv * wv.w + bv0.w;
                    float iv = sigf(gi), fv = sigf(gf), gv = tanhf_(gg), ov = sigf(go);
                    float c = fv * c0[mt * 4 + r] + iv * gv;
                    c0[mt * 4 + r] = c;
                    float h = ov * tanhf_(c);
                    hA0[nxt * 4096 + (u >> 3) * 256 + m * 8 + (u & 7)] = (_Float16)h;
                }
            }
        }
        __syncthreads();   // new h0 visible; all reads of cur buffers done

        // ===== layer 1 matmul, pass 1: h0_new @ Wih1 =====
        #pragma unroll
        for (int mt = 0; mt < 2; ++mt)
            #pragma unroll
            for (int t4 = 0; t4 < 4; ++t4) acc[mt][t4] = (f32x4){0.f, 0.f, 0.f, 0.f};
        #pragma unroll 1
        for (int ks = 0; ks < 4; ++ks) {
            const int a0o = nxt * 4096 + (ks * 4 + l16) * 256 + l15 * 8;   // new h0
            half8 a0 = *(const half8*)(hA0 + a0o);
            half8 a1 = *(const half8*)(hA0 + a0o + 128);
            #pragma unroll
            for (int t4 = 0; t4 < 4; ++t4) {
                half8 b = *(const half8*)(wfb1 + ks * 16384 + t4 * 4096);
                acc[0][t4] = MFMA(a0, b, acc[0][t4]);
                acc[1][t4] = MFMA(a1, b, acc[1][t4]);
            }
        }
        // ===== layer 1 matmul, pass 2: h1_old @ Whh1 (accumulate) =====
        #pragma unroll 1
        for (int ks = 0; ks < 4; ++ks) {
            const int a1o = cur * 4096 + (ks * 4 + l16) * 256 + l15 * 8;   // old h1
            half8 a0 = *(const half8*)(hA1 + a1o);
            half8 a1 = *(const half8*)(hA1 + a1o + 128);
            #pragma unroll
            for (int t4 = 0; t4 < 4; ++t4) {
                half8 b = *(const half8*)(wfb2 + ks * 16384 + t4 * 4096);
                acc[0][t4] = MFMA(a0, b, acc[0][t4]);
                acc[1][t4] = MFMA(a1, b, acc[1][t4]);
            }
        }
        // ===== layer 1 update =====
        {
            float4 bv1 = *(const float4*)(b1q + u * 4);
            #pragma unroll
            for (int mt = 0; mt < 2; ++mt) {
                #pragma unroll
                for (int r = 0; r < 4; ++r) {
                    int m = mt * 16 + l16 * 4 + r;
                    float gi = acc[mt][0][r] + bv1.x;
                    float gf = acc[mt][1][r] + bv1.y;
                    float gg = acc[mt][2][r] + bv1.z;
                    float go = acc[mt][3][r] + bv1.w;
                    float iv = sigf(gi), fv = sigf(gf), gv = tanhf_(gg), ov = sigf(go);
                    float c = fv * c1[mt * 4 + r] + iv * gv;
                    c1[mt * 4 + r] = c;
                    float h = ov * tanhf_(c);
                    hA1[nxt * 4096 + (u >> 3) * 256 + m * 8 + (u & 7)] = (_Float16)h;
                }
            }
        }
        __syncthreads();   // new h1 visible
        cur = nxt;
    }

    // ===== FC head =====
    float* hidb = (float*)hA0;           // overlay: hid [32][33] (4224 B)
    float hv[2];
    #pragma unroll
    for (int r2 = 0; r2 < 2; ++r2) {
        int task = tid + r2 * 512;       // 0..1023 = 32 seq x 32 j
        int s = task >> 5, j = task & 31;
        float sum = fc1_b[j];
        const float* wrow = fc1_w + j * HID;
        #pragma unroll 4
        for (int kq = 0; kq < 16; ++kq) {
            half8 H = *(const half8*)(hA1 + cur * 4096 + kq * 256 + s * 8);
            #pragma unroll
            for (int j8 = 0; j8 < 8; ++j8)
                sum += (float)H[j8] * wrow[kq * 8 + j8];
        }
        hv[r2] = fmaxf(sum, 0.f);
    }
    __syncthreads();                     // hA0 region free for overlay
    #pragma unroll
    for (int r2 = 0; r2 < 2; ++r2) {
        int task = tid + r2 * 512;
        hidb[(task >> 5) * 33 + (task & 31)] = hv[r2];
    }
    __syncthreads();
    if (tid < SEQB) {
        float sum = fc2_b[0];
        #pragma unroll
        for (int j = 0; j < 32; ++j) sum += hidb[tid * 33 + j] * fc2_w[j];
        out[seq0 + tid] = fmaxf(sum, 0.f);
    }
}

// ---------------------------------------------------------------------------
extern "C" void kernel_launch(void* const* d_in, const int* in_sizes, int n_in,
                              void* d_out, int out_size, void* d_ws, size_t ws_size,
                              hipStream_t stream)
{
    const float* g_data = (const float*)d_in[0];
    const float* weights = (const float*)d_in[1];
    const float* Wih0   = (const float*)d_in[2];
    const float* Whh0   = (const float*)d_in[3];
    const float* bih0   = (const float*)d_in[4];
    const float* bhh0   = (const float*)d_in[5];
    const float* Wih1   = (const float*)d_in[6];
    const float* Whh1   = (const float*)d_in[7];
    const float* bih1   = (const float*)d_in[8];
    const float* bhh1   = (const float*)d_in[9];
    const float* fc1_w  = (const float*)d_in[10];
    const float* fc1_b  = (const float*)d_in[11];
    const float* fc2_w  = (const float*)d_in[12];
    const float* fc2_b  = (const float*)d_in[13];
    float* out = (float*)d_out;

    float* ws = (float*)d_ws;
    float*     x    = ws;                              // 497664 f
    _Float16*  WF0  = (_Float16*)(x + NSEQ * T_STEPS); // 65536 h
    _Float16*  WF1i = WF0 + 65536;                     // 65536 h
    _Float16*  WF1h = WF1i + 65536;                    // 65536 h
    float*     wqp  = (float*)(WF1h + 65536);          // 512 f
    float*     b0q  = wqp + 512;                       // 512 f
    float*     b1q  = b0q + 512;                       // 512 f

    prep_kernel<<<774, 256, 0, stream>>>(Whh0, Wih1, Whh1, Wih0, bih0, bhh0, bih1, bhh1,
                                         WF0, WF1i, WF1h, wqp, b0q, b1q);
    income_kernel<<<1944, 256, 0, stream>>>(g_data, weights, x);
    lstm_main<<<NSEQ / SEQB, 512, 0, stream>>>(x, WF0, WF1i, WF1h, wqp, b0q, b1q,
                                               fc1_w, fc1_b, fc2_w, fc2_b, out);
}

// Round 12
// 383.301 us; speedup vs baseline: 3.9719x; 1.1447x over previous
//
#include <hip/hip_runtime.h>
#include <math.h>

#define NODES 81
#define T_STEPS 12
#define NSEQ 41472
#define HID 128
#define SEQB 16               // sequences per block

typedef unsigned short ushort;
typedef unsigned int uint;
typedef __attribute__((ext_vector_type(8))) _Float16 half8;
typedef __attribute__((ext_vector_type(4))) float f32x4;

#define MFMA(A, B, C) __builtin_amdgcn_mfma_f32_16x16x32_f16((A), (B), (C), 0, 0, 0)

// fast sigmoid/tanh: v_exp_f32 (2^x) + v_rcp_f32, ~2e-7 rel err
__device__ __forceinline__ float sigf(float v) {
    return __builtin_amdgcn_rcpf(1.f + __builtin_amdgcn_exp2f(v * -1.442695041f));
}
__device__ __forceinline__ float tanhf_(float v) {
    return fmaf(2.f, __builtin_amdgcn_rcpf(1.f + __builtin_amdgcn_exp2f(v * -2.885390082f)), -1.f);
}

// ---------------------------------------------------------------------------
// Prep: MFMA-fragment-major fp16 weights, ORIGINAL gate order (verified R10).
// Layout per matrix: [ks(4)][nt(32)][lane(64)][j(8)] _Float16,
// value = W[n*128+k]; k = ks*32 + (lane>>4)*8 + j, n = nt*16 + (lane&15).
// Gate type t4, unit-group gr of a tile: nt = t4*8 + gr.
// Plus per-unit packed float4 params: wq/b0q/b1q[u*4+t4] (fp32, exact).
// ---------------------------------------------------------------------------
__global__ void prep_kernel(const float* __restrict__ Whh0,
                            const float* __restrict__ Wih1,
                            const float* __restrict__ Whh1,
                            const float* __restrict__ Wih0,
                            const float* __restrict__ bih0, const float* __restrict__ bhh0,
                            const float* __restrict__ bih1, const float* __restrict__ bhh1,
                            _Float16* __restrict__ WF0,
                            _Float16* __restrict__ WF1i,
                            _Float16* __restrict__ WF1h,
                            float* __restrict__ wq,
                            float* __restrict__ b0q,
                            float* __restrict__ b1q)
{
    int idx = blockIdx.x * 256 + threadIdx.x;   // 198144 total, exact
    if (idx < 196608) {
        int mat = idx >> 16;              // 65536 per matrix
        int li  = idx & 65535;
        int j   = li & 7;
        int l   = (li >> 3) & 63;
        int nt  = (li >> 9) & 31;
        int ks  = li >> 14;
        int k = ks * 32 + (l >> 4) * 8 + j;
        int n = nt * 16 + (l & 15);
        const float* W = (mat == 0) ? Whh0 : (mat == 1 ? Wih1 : Whh1);
        _Float16* D = (mat == 0) ? WF0 : (mat == 1 ? WF1i : WF1h);
        D[li] = (_Float16)W[n * 128 + k];
    } else if (idx < 197120) {
        int jp = idx - 196608;
        int u = jp >> 2, t4 = jp & 3;
        wq[jp] = Wih0[t4 * 128 + u];
    } else if (idx < 197632) {
        int jp = idx - 197120;
        int u = jp >> 2, t4 = jp & 3;
        b0q[jp] = bih0[t4 * 128 + u] + bhh0[t4 * 128 + u];
    } else if (idx < 198144) {
        int jp = idx - 197632;
        int u = jp >> 2, t4 = jp & 3;
        b1q[jp] = bih1[t4 * 128 + u] + bhh1[t4 * 128 + u];
    }
}

// ---------------------------------------------------------------------------
// income = einsum('bta,an->bnt'); stored t-major: x[t][seq], seq = b*81+n
// ---------------------------------------------------------------------------
__global__ void income_kernel(const float* __restrict__ g_data,
                              const float* __restrict__ w,
                              float* __restrict__ x)
{
    int idx = blockIdx.x * 256 + threadIdx.x;   // 497664 exactly
    int n = idx % NODES;
    int r = idx / NODES;
    int t = r % T_STEPS;
    int b = r / T_STEPS;
    const float* grow = g_data + (b * T_STEPS + t) * NODES;
    float s = 0.f;
    #pragma unroll 3
    for (int a = 0; a < NODES; ++a)
        s += grow[a] * w[a * NODES + n];
    x[t * NSEQ + b * NODES + n] = s;
}

// ---------------------------------------------------------------------------
// Fused 2-layer LSTM + FC head on fp16 MFMA, WEIGHTS-IN-REGISTERS version.
// The 48 B-fragments (3 matrices x 4 ks x 4 t4 = 192 VGPR) are step-invariant
// -> loaded ONCE before the T-loop; the hot loop has zero global loads.
// Block = 16 seqs, 512 threads = 8 waves. Wave gr owns unit-group gr:
// n-tiles {gr, gr+8, gr+16, gr+24} (= i,f,g,o) x 1 m-tile; acc = 16 VGPR.
// h-state double-buffered fp16 in LDS: hA[buf][kq16][m16][j8], 16 KB total.
// ONE barrier per step (each RAW/WAR pair between h buffers is separated by
// the post-L0-update barrier of the step in between; verified by case table).
// ---------------------------------------------------------------------------
__global__ __launch_bounds__(512, 1) void lstm_main(
    const float* __restrict__ x,        // [12][NSEQ]
    const _Float16* __restrict__ WF0,
    const _Float16* __restrict__ WF1i,
    const _Float16* __restrict__ WF1h,
    const float* __restrict__ wq,       // [128][4] packed per-unit
    const float* __restrict__ b0q,      // [128][4]
    const float* __restrict__ b1q,      // [128][4]
    const float* __restrict__ fc1_w,    // [32][128]
    const float* __restrict__ fc1_b,    // [32]
    const float* __restrict__ fc2_w,    // [32]
    const float* __restrict__ fc2_b,    // [1]
    float* __restrict__ out)            // [NSEQ]
{
    __shared__ __align__(16) _Float16 hA0[4096];   // [2][kq16][m16][j8]
    __shared__ __align__(16) _Float16 hA1[4096];

    const int tid = threadIdx.x;
    const int l   = tid & 63;
    const int gr  = tid >> 6;          // 0..7 unit-group
    const int l15 = l & 15;
    const int l16 = l >> 4;
    const int u   = gr * 16 + l15;     // owned unit 0..127
    const int seq0 = blockIdx.x * SEQB;

    for (int i = tid; i < 2048; i += 512) {
        ((uint*)hA0)[i] = 0u; ((uint*)hA1)[i] = 0u;
    }

    // ---- load all 48 step-invariant B fragments into registers ----
    const _Float16* wfb0 = WF0  + gr * 512 + l * 8;
    const _Float16* wfb1 = WF1i + gr * 512 + l * 8;
    const _Float16* wfb2 = WF1h + gr * 512 + l * 8;
    half8 B0[4][4], B1[4][4], B2[4][4];   // [ks][t4], fully static indexing
    #pragma unroll
    for (int ks = 0; ks < 4; ++ks)
        #pragma unroll
        for (int t4 = 0; t4 < 4; ++t4) {
            B0[ks][t4] = *(const half8*)(wfb0 + ks * 16384 + t4 * 4096);
            B1[ks][t4] = *(const half8*)(wfb1 + ks * 16384 + t4 * 4096);
            B2[ks][t4] = *(const half8*)(wfb2 + ks * 16384 + t4 * 4096);
        }

    const float4 wv  = *(const float4*)(wq  + u * 4);
    const float4 bv0 = *(const float4*)(b0q + u * 4);
    const float4 bv1 = *(const float4*)(b1q + u * 4);

    float c0[4], c1[4];                 // [r]
    #pragma unroll
    for (int i = 0; i < 4; ++i) { c0[i] = 0.f; c1[i] = 0.f; }
    __syncthreads();

    const int wrbase = (u >> 3) * 128 + (u & 7);   // h-write base (fp16 elems)

    int cur = 0;
    for (int t = 0; t < T_STEPS; ++t) {
        const int nxt = cur ^ 1;
        const float4 xv4 = *(const float4*)(x + t * NSEQ + seq0 + l16 * 4);

        f32x4 acc[4];                   // [gate-type]

        // ===== layer 0 matmul: h0 @ Whh0 =====
        #pragma unroll
        for (int t4 = 0; t4 < 4; ++t4) acc[t4] = (f32x4){0.f, 0.f, 0.f, 0.f};
        #pragma unroll
        for (int ks = 0; ks < 4; ++ks) {
            half8 a = *(const half8*)(hA0 + cur * 2048 + (ks * 4 + l16) * 128 + l15 * 8);
            #pragma unroll
            for (int t4 = 0; t4 < 4; ++t4) acc[t4] = MFMA(a, B0[ks][t4], acc[t4]);
        }
        // ===== layer 0 update (in-register activation) =====
        #pragma unroll
        for (int r = 0; r < 4; ++r) {
            int m = l16 * 4 + r;
            float gi = acc[0][r] + xv4[r] * wv.x + bv0.x;
            float gf = acc[1][r] + xv4[r] * wv.y + bv0.y;
            float gg = acc[2][r] + xv4[r] * wv.z + bv0.z;
            float go = acc[3][r] + xv4[r] * wv.w + bv0.w;
            float iv = sigf(gi), fv = sigf(gf), gv = tanhf_(gg), ov = sigf(go);
            float c = fv * c0[r] + iv * gv;
            c0[r] = c;
            hA0[nxt * 2048 + wrbase + m * 8] = (_Float16)(ov * tanhf_(c));
        }
        __syncthreads();   // the ONE barrier: new h0 visible; prior reads done

        // ===== layer 1 matmul: h0_new @ Wih1 + h1_old @ Whh1 =====
        #pragma unroll
        for (int t4 = 0; t4 < 4; ++t4) acc[t4] = (f32x4){0.f, 0.f, 0.f, 0.f};
        #pragma unroll
        for (int ks = 0; ks < 4; ++ks) {
            half8 a = *(const half8*)(hA0 + nxt * 2048 + (ks * 4 + l16) * 128 + l15 * 8);
            #pragma unroll
            for (int t4 = 0; t4 < 4; ++t4) acc[t4] = MFMA(a, B1[ks][t4], acc[t4]);
        }
        #pragma unroll
        for (int ks = 0; ks < 4; ++ks) {
            half8 a = *(const half8*)(hA1 + cur * 2048 + (ks * 4 + l16) * 128 + l15 * 8);
            #pragma unroll
            for (int t4 = 0; t4 < 4; ++t4) acc[t4] = MFMA(a, B2[ks][t4], acc[t4]);
        }
        // ===== layer 1 update =====
        #pragma unroll
        for (int r = 0; r < 4; ++r) {
            int m = l16 * 4 + r;
            float gi = acc[0][r] + bv1.x;
            float gf = acc[1][r] + bv1.y;
            float gg = acc[2][r] + bv1.z;
            float go = acc[3][r] + bv1.w;
            float iv = sigf(gi), fv = sigf(gf), gv = tanhf_(gg), ov = sigf(go);
            float c = fv * c1[r] + iv * gv;
            c1[r] = c;
            hA1[nxt * 2048 + wrbase + m * 8] = (_Float16)(ov * tanhf_(c));
        }
        // no second barrier: next step's post-L0 barrier separates all pairs
        cur = nxt;
    }
    __syncthreads();                    // final h1 visible to all waves

    // ===== FC head: 512 tasks = 16 seq x 32 j, one per thread =====
    float* hidb = (float*)hA0;          // overlay: hid [16][33]
    {
        int s = tid >> 5, j = tid & 31;
        float sum = fc1_b[j];
        const float* wrow = fc1_w + j * HID;
        #pragma unroll 4
        for (int kq = 0; kq < 16; ++kq) {
            half8 H = *(const half8*)(hA1 + cur * 2048 + kq * 128 + s * 8);
            #pragma unroll
            for (int j8 = 0; j8 < 8; ++j8)
                sum += (float)H[j8] * wrow[kq * 8 + j8];
        }
        float hv = fmaxf(sum, 0.f);
        __syncthreads();                // hA0 region free for overlay
        hidb[s * 33 + j] = hv;
    }
    __syncthreads();
    if (tid < SEQB) {
        float sum = fc2_b[0];
        #pragma unroll
        for (int j = 0; j < 32; ++j) sum += hidb[tid * 33 + j] * fc2_w[j];
        out[seq0 + tid] = fmaxf(sum, 0.f);
    }
}

// ---------------------------------------------------------------------------
extern "C" void kernel_launch(void* const* d_in, const int* in_sizes, int n_in,
                              void* d_out, int out_size, void* d_ws, size_t ws_size,
                              hipStream_t stream)
{
    const float* g_data = (const float*)d_in[0];
    const float* weights = (const float*)d_in[1];
    const float* Wih0   = (const float*)d_in[2];
    const float* Whh0   = (const float*)d_in[3];
    const float* bih0   = (const float*)d_in[4];
    const float* bhh0   = (const float*)d_in[5];
    const float* Wih1   = (const float*)d_in[6];
    const float* Whh1   = (const float*)d_in[7];
    const float* bih1   = (const float*)d_in[8];
    const float* bhh1   = (const float*)d_in[9];
    const float* fc1_w  = (const float*)d_in[10];
    const float* fc1_b  = (const float*)d_in[11];
    const float* fc2_w  = (const float*)d_in[12];
    const float* fc2_b  = (const float*)d_in[13];
    float* out = (float*)d_out;

    float* ws = (float*)d_ws;
    float*     x    = ws;                              // 497664 f
    _Float16*  WF0  = (_Float16*)(x + NSEQ * T_STEPS); // 65536 h
    _Float16*  WF1i = WF0 + 65536;                     // 65536 h
    _Float16*  WF1h = WF1i + 65536;                    // 65536 h
    float*     wqp  = (float*)(WF1h + 65536);          // 512 f
    float*     b0q  = wqp + 512;                       // 512 f
    float*     b1q  = b0q + 512;                       // 512 f

    prep_kernel<<<774, 256, 0, stream>>>(Whh0, Wih1, Whh1, Wih0, bih0, bhh0, bih1, bhh1,
                                         WF0, WF1i, WF1h, wqp, b0q, b1q);
    income_kernel<<<1944, 256, 0, stream>>>(g_data, weights, x);
    lstm_main<<<NSEQ / SEQB, 512, 0, stream>>>(x, WF0, WF1i, WF1h, wqp, b0q, b1q,
                                               fc1_w, fc1_b, fc2_w, fc2_b, out);
}